// Round 1
// baseline (258.023 us; speedup 1.0000x reference)
//
#include <hip/hip_runtime.h>
#include <math.h>

#define NB 256
#define NN 64
#define ND 64
#define NH 16
#define NHEAD 4
#define TOT (NB*NN*ND)           // 1048576
#define EPS_SINK 1e-8f
#define THR (1.0f/64.0f)
#define INV_BSCALE 0.5412658773652741f   // 1/sqrt(2+sqrt(2))
#define UNTANH_A 0.6f

static __device__ __forceinline__ float buntanh(float x) {
    return (tanhf(x) + UNTANH_A * x) * INV_BSCALE;
}

// ---------------------------------------------------------------------------
// K1: pred/keys/queries = buntanh(state[b,n,:] @ w[b,n,:,:])
// One wave per (weight, bn) task. lane: k4=lane&15 owns output cols 4k4..4k4+3,
// jg=lane>>4 covers j in [16jg, 16jg+16). shfl_xor(16,32) reduce over jg.
// ---------------------------------------------------------------------------
__global__ __launch_bounds__(256) void gemv_buntanh_kernel(
    const float* __restrict__ state,
    const float* __restrict__ w1, const float* __restrict__ w2,
    const float* __restrict__ w3,
    float* __restrict__ pred, float* __restrict__ keys,
    float* __restrict__ quer)
{
    const int wave = threadIdx.x >> 6;
    const int lane = threadIdx.x & 63;
    const int g = blockIdx.x * 4 + wave;          // 0..49151
    const int widx = g >> 14;                     // 0,1,2
    const int bn = g & 16383;

    const float* __restrict__ w = (widx == 0) ? w1 : (widx == 1) ? w2 : w3;
    float* __restrict__ outp = (widx == 0) ? pred : (widx == 1) ? keys : quer;

    const int k4 = lane & 15;
    const int jg = lane >> 4;

    // state fragment: s[j] for j in [16jg, 16jg+16)
    const float* sp = state + bn * 64 + jg * 16;
    float s[16];
#pragma unroll
    for (int i = 0; i < 4; ++i) {
        float4 v = *(const float4*)(sp + 4 * i);
        s[4 * i + 0] = v.x; s[4 * i + 1] = v.y;
        s[4 * i + 2] = v.z; s[4 * i + 3] = v.w;
    }

    const float* wp = w + (size_t)bn * 4096 + (size_t)(jg * 16) * 64 + k4 * 4;
    float4 acc = make_float4(0.f, 0.f, 0.f, 0.f);
#pragma unroll
    for (int jj = 0; jj < 16; ++jj) {
        float4 wv = *(const float4*)(wp + jj * 64);
        acc.x = fmaf(s[jj], wv.x, acc.x);
        acc.y = fmaf(s[jj], wv.y, acc.y);
        acc.z = fmaf(s[jj], wv.z, acc.z);
        acc.w = fmaf(s[jj], wv.w, acc.w);
    }
    // reduce over jg (lane bits 4,5)
#pragma unroll
    for (int o = 16; o <= 32; o <<= 1) {
        acc.x += __shfl_xor(acc.x, o, 64);
        acc.y += __shfl_xor(acc.y, o, 64);
        acc.z += __shfl_xor(acc.z, o, 64);
        acc.w += __shfl_xor(acc.w, o, 64);
    }
    if (jg == 0) {
        float4 o4;
        o4.x = buntanh(acc.x);
        o4.y = buntanh(acc.y);
        o4.z = buntanh(acc.z);
        o4.w = buntanh(acc.w);
        *(float4*)(outp + bn * 64 + k4 * 4) = o4;
    }
}

// ---------------------------------------------------------------------------
// K2: per (b,h): scores -> rmsnorm -> sinkhorn(10) -> threshold -> A@V -> target
// ---------------------------------------------------------------------------
__global__ __launch_bounds__(256) void attn_sinkhorn_kernel(
    const float* __restrict__ pred, const float* __restrict__ keys,
    const float* __restrict__ quer, float* __restrict__ target)
{
    __shared__ float4 Qs[64];
    __shared__ float4 Ks[64];
    __shared__ float4 Vs[64];
    __shared__ float P[64 * 65];
    __shared__ float redS[4], redM[4];

    const int blk = blockIdx.x;     // b*16 + h
    const int b = blk >> 4;
    const int h = blk & 15;
    const int t = threadIdx.x;

    {
        const int r = t & 63;
        const int which = t >> 6;   // 0:Q 1:K 2:V 3:idle
        const size_t off = ((size_t)(b * 64 + r)) * 64 + h * 4;
        if (which == 0)      Qs[r] = *(const float4*)(quer + off);
        else if (which == 1) Ks[r] = *(const float4*)(keys + off);
        else if (which == 2) Vs[r] = *(const float4*)(pred + off);
    }
    __syncthreads();

    // scores kept in registers; accumulate sum-of-squares and max
    const int m = t & 63;
    const int n0 = t >> 6;
    float ev[16];
    float ss = 0.f, mx = -1e30f;
    {
        const float4 k4 = Ks[m];
#pragma unroll
        for (int i = 0; i < 16; ++i) {
            const int n = n0 + 4 * i;
            const float4 q4 = Qs[n];
            float e = (q4.x * k4.x + q4.y * k4.y + q4.z * k4.z + q4.w * k4.w) * 0.5f;
            ev[i] = e;
            ss += e * e;
            mx = fmaxf(mx, e);
        }
    }
#pragma unroll
    for (int o = 32; o >= 1; o >>= 1) {
        ss += __shfl_xor(ss, o, 64);
        mx = fmaxf(mx, __shfl_xor(mx, o, 64));
    }
    {
        const int wv = t >> 6, ln = t & 63;
        if (ln == 0) { redS[wv] = ss; redM[wv] = mx; }
    }
    __syncthreads();
    ss = redS[0] + redS[1] + redS[2] + redS[3];
    mx = fmaxf(fmaxf(redM[0], redM[1]), fmaxf(redM[2], redM[3]));
    const float scale = rsqrtf(ss * (1.0f / 4096.0f) + 1e-6f);  // SHARPNESS=1

    // p = exp(scale*(e - mx))
#pragma unroll
    for (int i = 0; i < 16; ++i) {
        const int n = n0 + 4 * i;
        P[n * 65 + m] = expf(scale * (ev[i] - mx));
    }
    __syncthreads();

    // sinkhorn: 10 x (row-normalize, col-normalize)
    const int rn = t >> 2;      // row/col index 0..63
    const int rq = t & 3;       // quarter 0..3
    for (int it = 0; it < 10; ++it) {
        float s1 = 0.f;
#pragma unroll
        for (int j = 0; j < 16; ++j) s1 += P[rn * 65 + rq * 16 + j];
        s1 += __shfl_xor(s1, 1, 64);
        s1 += __shfl_xor(s1, 2, 64);
        float inv = 1.0f / (s1 + EPS_SINK);
#pragma unroll
        for (int j = 0; j < 16; ++j) P[rn * 65 + rq * 16 + j] *= inv;
        __syncthreads();

        float s2 = 0.f;
#pragma unroll
        for (int j = 0; j < 16; ++j) s2 += P[(rq * 16 + j) * 65 + rn];
        s2 += __shfl_xor(s2, 1, 64);
        s2 += __shfl_xor(s2, 2, 64);
        inv = 1.0f / (s2 + EPS_SINK);
#pragma unroll
        for (int j = 0; j < 16; ++j) P[(rq * 16 + j) * 65 + rn] *= inv;
        __syncthreads();
    }

    // routed_V: target[b,n,h*4+d] = sum_m (P>1/64 ? P : 0) * V[m][d]
    {
        const int d = t & 3;
        const int n = t >> 2;
        const float* Vf = (const float*)Vs;
        float acc = 0.f;
#pragma unroll 8
        for (int mm = 0; mm < 64; ++mm) {
            float p = P[n * 65 + mm];
            float a = (p > THR) ? p : 0.f;
            acc = fmaf(a, Vf[mm * 4 + d], acc);
        }
        target[((size_t)(b * 64 + n)) * 64 + h * 4 + d] = acc;
    }
}

// ---------------------------------------------------------------------------
// K3: per-block partial sums of the three squared-error losses
// ---------------------------------------------------------------------------
__global__ __launch_bounds__(256) void loss_partial_kernel(
    const float* __restrict__ pred, const float* __restrict__ keys,
    const float* __restrict__ quer, const float* __restrict__ target,
    const float* __restrict__ state, const float* __restrict__ env,
    float* __restrict__ part)
{
    float a1 = 0.f, a2 = 0.f, a3 = 0.f;
    for (int e = blockIdx.x * 256 + threadIdx.x; e < TOT; e += 1024 * 256) {
        const int b = e >> 12;
        const int rem = e & 4095;
        const int n = rem >> 6;
        const int c = rem & 63;
        float tv;
        if (n >= 2) {
            tv = target[e];
        } else {
            const int idx = n * 64 + c;
            tv = (idx < 100) ? env[b * 100 + idx] : 0.f;
        }
        const float p = pred[e];
        const float k = keys[e];
        const float q = quer[e];
        const float s = state[e];
        const float d1 = p - tv; a1 = fmaf(d1, d1, a1);
        const float d2 = k - s;  a2 = fmaf(d2, d2, a2);
        const float d3 = q - tv; a3 = fmaf(d3, d3, a3);
    }
#pragma unroll
    for (int o = 32; o >= 1; o >>= 1) {
        a1 += __shfl_xor(a1, o, 64);
        a2 += __shfl_xor(a2, o, 64);
        a3 += __shfl_xor(a3, o, 64);
    }
    __shared__ float red[12];
    const int wv = threadIdx.x >> 6, ln = threadIdx.x & 63;
    if (ln == 0) { red[wv] = a1; red[4 + wv] = a2; red[8 + wv] = a3; }
    __syncthreads();
    if (threadIdx.x == 0) {
        part[blockIdx.x]        = red[0] + red[1] + red[2] + red[3];
        part[1024 + blockIdx.x] = red[4] + red[5] + red[6] + red[7];
        part[2048 + blockIdx.x] = red[8] + red[9] + red[10] + red[11];
    }
}

// ---------------------------------------------------------------------------
// K4: final reduce -> scalar loss
// ---------------------------------------------------------------------------
__global__ __launch_bounds__(256) void loss_final_kernel(
    const float* __restrict__ part, float* __restrict__ out)
{
    float a = 0.f;
    for (int i = threadIdx.x; i < 3072; i += 256) a += part[i];
#pragma unroll
    for (int o = 32; o >= 1; o >>= 1) a += __shfl_xor(a, o, 64);
    __shared__ float red[4];
    const int wv = threadIdx.x >> 6, ln = threadIdx.x & 63;
    if (ln == 0) red[wv] = a;
    __syncthreads();
    if (threadIdx.x == 0) {
        out[0] = (red[0] + red[1] + red[2] + red[3]) * (1.0f / (float)TOT);
    }
}

extern "C" void kernel_launch(void* const* d_in, const int* in_sizes, int n_in,
                              void* d_out, int out_size, void* d_ws, size_t ws_size,
                              hipStream_t stream)
{
    const float* env   = (const float*)d_in[0];
    const float* state = (const float*)d_in[1];
    const float* w1    = (const float*)d_in[2];
    const float* w2    = (const float*)d_in[3];
    const float* w3    = (const float*)d_in[4];
    float* out = (float*)d_out;

    float* wsf    = (float*)d_ws;
    float* pred   = wsf;
    float* keys   = wsf + 1 * TOT;
    float* quer   = wsf + 2 * TOT;
    float* target = wsf + 3 * TOT;
    float* part   = wsf + 4 * TOT;   // 3*1024 floats

    hipLaunchKernelGGL(gemv_buntanh_kernel, dim3(12288), dim3(256), 0, stream,
                       state, w1, w2, w3, pred, keys, quer);
    hipLaunchKernelGGL(attn_sinkhorn_kernel, dim3(4096), dim3(256), 0, stream,
                       pred, keys, quer, target);
    hipLaunchKernelGGL(loss_partial_kernel, dim3(1024), dim3(256), 0, stream,
                       pred, keys, quer, target, state, env, part);
    hipLaunchKernelGGL(loss_final_kernel, dim3(1), dim3(256), 0, stream,
                       part, out);
}

// Round 3
// 251.865 us; speedup vs baseline: 1.0245x; 1.0245x over previous
//
#include <hip/hip_runtime.h>
#include <math.h>

#define NB 256
#define NN 64
#define ND 64
#define NH 16
#define TOT (NB*NN*ND)           // 1048576
#define EPS_SINK 1e-8f
#define THR (1.0f/64.0f)
#define INV_BSCALE 0.5412658773652741f   // 1/sqrt(2+sqrt(2))
#define UNTANH_A 0.6f

typedef float nativef4 __attribute__((ext_vector_type(4)));

static __device__ __forceinline__ float buntanh(float x) {
    return (tanhf(x) + UNTANH_A * x) * INV_BSCALE;
}

// ---------------------------------------------------------------------------
// K1 v2: pred/keys/queries = buntanh(state[b,n,:] @ w[b,n,:,:])
// One wave per 4 consecutive tasks (64 KB contiguous weight stream per wave).
// Weight loads are nontemporal (streamed once, don't pollute L2/L3).
// lane: k4=lane&15 owns output cols 4k4..4k4+3, jg=lane>>4 covers j in
// [16jg,16jg+16). shfl_xor(16,32) reduce over jg.
// ---------------------------------------------------------------------------
__global__ __launch_bounds__(256, 4) void gemv_buntanh_kernel(
    const float* __restrict__ state,
    const float* __restrict__ w1, const float* __restrict__ w2,
    const float* __restrict__ w3,
    float* __restrict__ pred, float* __restrict__ keys,
    float* __restrict__ quer)
{
    const int wave = threadIdx.x >> 6;
    const int lane = threadIdx.x & 63;
    const int wgid = blockIdx.x * 4 + wave;       // 0..12287
    const int k4 = lane & 15;
    const int jg = lane >> 4;
    const int task0 = wgid * 4;                   // 4 consecutive tasks

#pragma unroll
    for (int tt = 0; tt < 4; ++tt) {
        const int task = task0 + tt;              // 0..49151
        const int widx = task >> 14;              // 0,1,2
        const int bn = task & 16383;

        const float* __restrict__ w = (widx == 0) ? w1 : (widx == 1) ? w2 : w3;
        float* __restrict__ outp = (widx == 0) ? pred : (widx == 1) ? keys : quer;

        // state fragment: s[j] for j in [16jg, 16jg+16)
        const float* sp = state + bn * 64 + jg * 16;
        float s[16];
#pragma unroll
        for (int i = 0; i < 4; ++i) {
            float4 v = *(const float4*)(sp + 4 * i);
            s[4 * i + 0] = v.x; s[4 * i + 1] = v.y;
            s[4 * i + 2] = v.z; s[4 * i + 3] = v.w;
        }

        const nativef4* wp = (const nativef4*)(w + (size_t)bn * 4096 +
                                               (size_t)(jg * 16) * 64 + k4 * 4);
        float accx = 0.f, accy = 0.f, accz = 0.f, accw = 0.f;
#pragma unroll
        for (int jj = 0; jj < 16; ++jj) {
            nativef4 wv = __builtin_nontemporal_load(wp + jj * 16);  // +64 floats
            accx = fmaf(s[jj], wv.x, accx);
            accy = fmaf(s[jj], wv.y, accy);
            accz = fmaf(s[jj], wv.z, accz);
            accw = fmaf(s[jj], wv.w, accw);
        }
        // reduce over jg (lane bits 4,5)
#pragma unroll
        for (int o = 16; o <= 32; o <<= 1) {
            accx += __shfl_xor(accx, o, 64);
            accy += __shfl_xor(accy, o, 64);
            accz += __shfl_xor(accz, o, 64);
            accw += __shfl_xor(accw, o, 64);
        }
        if (jg == 0) {
            float4 o4;
            o4.x = buntanh(accx);
            o4.y = buntanh(accy);
            o4.z = buntanh(accz);
            o4.w = buntanh(accw);
            *(float4*)(outp + bn * 64 + k4 * 4) = o4;
        }
    }
}

// ---------------------------------------------------------------------------
// K2: per (b,h): scores -> rmsnorm -> sinkhorn(10) -> threshold -> A@V
//     -> fused loss partials (no target array ever written)
// ---------------------------------------------------------------------------
__global__ __launch_bounds__(256) void attn_sinkhorn_loss_kernel(
    const float* __restrict__ pred, const float* __restrict__ keys,
    const float* __restrict__ quer, const float* __restrict__ state,
    const float* __restrict__ env, float* __restrict__ part)
{
    __shared__ float4 Qs[64];
    __shared__ float4 Ks[64];
    __shared__ float4 Vs[64];
    __shared__ float4 Ss[64];
    __shared__ float P[64 * 65];
    __shared__ float redS[4], redM[4];
    __shared__ float red[12];

    const int blk = blockIdx.x;     // b*16 + h
    const int b = blk >> 4;
    const int h = blk & 15;
    const int t = threadIdx.x;

    {
        const int r = t & 63;
        const int which = t >> 6;   // 0:Q 1:K 2:V 3:state
        const size_t off = ((size_t)(b * 64 + r)) * 64 + h * 4;
        if (which == 0)      Qs[r] = *(const float4*)(quer + off);
        else if (which == 1) Ks[r] = *(const float4*)(keys + off);
        else if (which == 2) Vs[r] = *(const float4*)(pred + off);
        else                 Ss[r] = *(const float4*)(state + off);
    }
    __syncthreads();

    // scores kept in registers; accumulate sum-of-squares and max
    const int m = t & 63;
    const int n0 = t >> 6;
    float ev[16];
    float ss = 0.f, mx = -1e30f;
    {
        const float4 k4 = Ks[m];
#pragma unroll
        for (int i = 0; i < 16; ++i) {
            const int n = n0 + 4 * i;
            const float4 q4 = Qs[n];
            float e = (q4.x * k4.x + q4.y * k4.y + q4.z * k4.z + q4.w * k4.w) * 0.5f;
            ev[i] = e;
            ss += e * e;
            mx = fmaxf(mx, e);
        }
    }
#pragma unroll
    for (int o = 32; o >= 1; o >>= 1) {
        ss += __shfl_xor(ss, o, 64);
        mx = fmaxf(mx, __shfl_xor(mx, o, 64));
    }
    {
        const int wv = t >> 6, ln = t & 63;
        if (ln == 0) { redS[wv] = ss; redM[wv] = mx; }
    }
    __syncthreads();
    ss = redS[0] + redS[1] + redS[2] + redS[3];
    mx = fmaxf(fmaxf(redM[0], redM[1]), fmaxf(redM[2], redM[3]));
    const float scale = rsqrtf(ss * (1.0f / 4096.0f) + 1e-6f);  // SHARPNESS=1

    // p = exp(scale*(e - mx))
#pragma unroll
    for (int i = 0; i < 16; ++i) {
        const int n = n0 + 4 * i;
        P[n * 65 + m] = expf(scale * (ev[i] - mx));
    }
    __syncthreads();

    // sinkhorn: 10 x (row-normalize, col-normalize)
    const int rn = t >> 2;      // row/col index 0..63
    const int rq = t & 3;       // quarter 0..3
    for (int it = 0; it < 10; ++it) {
        float s1 = 0.f;
#pragma unroll
        for (int j = 0; j < 16; ++j) s1 += P[rn * 65 + rq * 16 + j];
        s1 += __shfl_xor(s1, 1, 64);
        s1 += __shfl_xor(s1, 2, 64);
        float inv = 1.0f / (s1 + EPS_SINK);
#pragma unroll
        for (int j = 0; j < 16; ++j) P[rn * 65 + rq * 16 + j] *= inv;
        __syncthreads();

        float s2 = 0.f;
#pragma unroll
        for (int j = 0; j < 16; ++j) s2 += P[(rq * 16 + j) * 65 + rn];
        s2 += __shfl_xor(s2, 1, 64);
        s2 += __shfl_xor(s2, 2, 64);
        inv = 1.0f / (s2 + EPS_SINK);
#pragma unroll
        for (int j = 0; j < 16; ++j) P[(rq * 16 + j) * 65 + rn] *= inv;
        __syncthreads();
    }

    // routed_V + fused loss partials for elements (b, n, h*4+d)
    float l1, l2, l3;
    {
        const int d = t & 3;
        const int n = t >> 2;
        const float* Vf = (const float*)Vs;
        const float* Kf = (const float*)Ks;
        const float* Qf = (const float*)Qs;
        const float* Sf = (const float*)Ss;
        float acc = 0.f;
#pragma unroll 8
        for (int mm = 0; mm < 64; ++mm) {
            float p = P[n * 65 + mm];
            float a = (p > THR) ? p : 0.f;
            acc = fmaf(a, Vf[mm * 4 + d], acc);
        }
        // target value for this element
        float tv;
        if (n == 0) {
            tv = env[b * 100 + h * 4 + d];
        } else if (n == 1) {
            const int idx = 64 + h * 4 + d;
            tv = (idx < 100) ? env[b * 100 + idx] : 0.f;
        } else {
            tv = acc;
        }
        const float p  = Vf[n * 4 + d];
        const float kk = Kf[n * 4 + d];
        const float q  = Qf[n * 4 + d];
        const float sv = Sf[n * 4 + d];
        const float d1 = p - tv;
        const float d2 = kk - sv;
        const float d3 = q - tv;
        l1 = d1 * d1; l2 = d2 * d2; l3 = d3 * d3;
    }
#pragma unroll
    for (int o = 32; o >= 1; o >>= 1) {
        l1 += __shfl_xor(l1, o, 64);
        l2 += __shfl_xor(l2, o, 64);
        l3 += __shfl_xor(l3, o, 64);
    }
    {
        const int wv = t >> 6, ln = t & 63;
        if (ln == 0) { red[wv] = l1; red[4 + wv] = l2; red[8 + wv] = l3; }
    }
    __syncthreads();
    if (t == 0) {
        part[blk]        = red[0] + red[1] + red[2] + red[3];
        part[4096 + blk] = red[4] + red[5] + red[6] + red[7];
        part[8192 + blk] = red[8] + red[9] + red[10] + red[11];
    }
}

// ---------------------------------------------------------------------------
// K3: final reduce -> scalar loss
// ---------------------------------------------------------------------------
__global__ __launch_bounds__(256) void loss_final_kernel(
    const float* __restrict__ part, float* __restrict__ out)
{
    float a = 0.f;
    for (int i = threadIdx.x; i < 12288; i += 256) a += part[i];
#pragma unroll
    for (int o = 32; o >= 1; o >>= 1) a += __shfl_xor(a, o, 64);
    __shared__ float red[4];
    const int wv = threadIdx.x >> 6, ln = threadIdx.x & 63;
    if (ln == 0) red[wv] = a;
    __syncthreads();
    if (threadIdx.x == 0) {
        out[0] = (red[0] + red[1] + red[2] + red[3]) * (1.0f / (float)TOT);
    }
}

extern "C" void kernel_launch(void* const* d_in, const int* in_sizes, int n_in,
                              void* d_out, int out_size, void* d_ws, size_t ws_size,
                              hipStream_t stream)
{
    const float* env   = (const float*)d_in[0];
    const float* state = (const float*)d_in[1];
    const float* w1    = (const float*)d_in[2];
    const float* w2    = (const float*)d_in[3];
    const float* w3    = (const float*)d_in[4];
    float* out = (float*)d_out;

    float* wsf  = (float*)d_ws;
    float* pred = wsf;
    float* keys = wsf + 1 * TOT;
    float* quer = wsf + 2 * TOT;
    float* part = wsf + 3 * TOT;   // 3*4096 floats

    hipLaunchKernelGGL(gemv_buntanh_kernel, dim3(3072), dim3(256), 0, stream,
                       state, w1, w2, w3, pred, keys, quer);
    hipLaunchKernelGGL(attn_sinkhorn_loss_kernel, dim3(4096), dim3(256), 0, stream,
                       pred, keys, quer, state, env, part);
    hipLaunchKernelGGL(loss_final_kernel, dim3(1), dim3(256), 0, stream,
                       part, out);
}

// Round 4
// 231.958 us; speedup vs baseline: 1.1124x; 1.0858x over previous
//
#include <hip/hip_runtime.h>
#include <math.h>

#define NB 256
#define NN 64
#define ND 64
#define TOT (NB*NN*ND)           // 1048576
#define EPS_SINK 1e-8f
#define THR (1.0f/64.0f)
#define INV_BSCALE 0.5412658773652741f   // 1/sqrt(2+sqrt(2))
#define UNTANH_A 0.6f

typedef float nativef4 __attribute__((ext_vector_type(4)));

static __device__ __forceinline__ float buntanh(float x) {
    return (tanhf(x) + UNTANH_A * x) * INV_BSCALE;
}

// ---------------------------------------------------------------------------
// K1 v3: pred/keys/queries = buntanh(state[b,n,:] @ w[b,n,:,:])
// One wave per 8 consecutive tasks (128 KB contiguous NT weight stream).
// Each 8-task group lies in a single weight tensor (16384 % 8 == 0), so the
// w/outp pointers are hoisted out of the task loop.
// ---------------------------------------------------------------------------
__global__ __launch_bounds__(256, 4) void gemv_buntanh_kernel(
    const float* __restrict__ state,
    const float* __restrict__ w1, const float* __restrict__ w2,
    const float* __restrict__ w3,
    float* __restrict__ pred, float* __restrict__ keys,
    float* __restrict__ quer)
{
    const int wave = threadIdx.x >> 6;
    const int lane = threadIdx.x & 63;
    const int wgid = blockIdx.x * 4 + wave;       // 0..6143
    const int k4 = lane & 15;
    const int jg = lane >> 4;
    const int task0 = wgid * 8;                   // 8 consecutive tasks
    const int widx = task0 >> 14;                 // 0,1,2 (uniform over group)
    const int bn0 = task0 & 16383;

    const float* __restrict__ w = (widx == 0) ? w1 : (widx == 1) ? w2 : w3;
    float* __restrict__ outp = (widx == 0) ? pred : (widx == 1) ? keys : quer;

#pragma unroll
    for (int tt = 0; tt < 8; ++tt) {
        const int bn = bn0 + tt;

        // state fragment: s[j] for j in [16jg, 16jg+16)
        const float* sp = state + bn * 64 + jg * 16;
        float s[16];
#pragma unroll
        for (int i = 0; i < 4; ++i) {
            float4 v = *(const float4*)(sp + 4 * i);
            s[4 * i + 0] = v.x; s[4 * i + 1] = v.y;
            s[4 * i + 2] = v.z; s[4 * i + 3] = v.w;
        }

        const nativef4* wp = (const nativef4*)(w + (size_t)bn * 4096 +
                                               (size_t)(jg * 16) * 64 + k4 * 4);
        float accx = 0.f, accy = 0.f, accz = 0.f, accw = 0.f;
#pragma unroll
        for (int jj = 0; jj < 16; ++jj) {
            nativef4 wv = __builtin_nontemporal_load(wp + jj * 16);  // +64 floats
            accx = fmaf(s[jj], wv.x, accx);
            accy = fmaf(s[jj], wv.y, accy);
            accz = fmaf(s[jj], wv.z, accz);
            accw = fmaf(s[jj], wv.w, accw);
        }
        // reduce over jg (lane bits 4,5)
#pragma unroll
        for (int o = 16; o <= 32; o <<= 1) {
            accx += __shfl_xor(accx, o, 64);
            accy += __shfl_xor(accy, o, 64);
            accz += __shfl_xor(accz, o, 64);
            accw += __shfl_xor(accw, o, 64);
        }
        if (jg == 0) {
            float4 o4;
            o4.x = buntanh(accx);
            o4.y = buntanh(accy);
            o4.z = buntanh(accz);
            o4.w = buntanh(accw);
            *(float4*)(outp + bn * 64 + k4 * 4) = o4;
        }
    }
}

// ---------------------------------------------------------------------------
// K2 v2: per (b,h): scores -> rmsnorm -> register-resident sinkhorn(10)
//        -> threshold -> A@V -> fused loss partials.
// 256 threads = 16x16 grid (tr,tc); thread owns P[4tr+i][4tc+j] in registers.
// Row-normalize: wave-local shfl_xor(1,2,4,8) (no LDS, no barrier).
// Col-normalize: shfl_xor(16,32) + 4x64-float LDS exchange, 1 barrier/iter
// (double-buffered cp).
// ---------------------------------------------------------------------------
__global__ __launch_bounds__(256) void attn_sinkhorn_loss_kernel(
    const float* __restrict__ pred, const float* __restrict__ keys,
    const float* __restrict__ quer, const float* __restrict__ state,
    const float* __restrict__ env, float* __restrict__ part)
{
    __shared__ float4 Qs[64];
    __shared__ float4 Ks[64];
    __shared__ float4 Vs[64];
    __shared__ float4 Ss[64];
    __shared__ float cp[2][4][64];
    __shared__ float P[64 * 65];
    __shared__ float redS[4], redM[4];
    __shared__ float red[12];

    const int blk = blockIdx.x;     // b*16 + h
    const int b = blk >> 4;
    const int h = blk & 15;
    const int t = threadIdx.x;

    {
        const int r = t & 63;
        const int which = t >> 6;   // 0:Q 1:K 2:V 3:state
        const size_t off = ((size_t)(b * 64 + r)) * 64 + h * 4;
        if (which == 0)      Qs[r] = *(const float4*)(quer + off);
        else if (which == 1) Ks[r] = *(const float4*)(keys + off);
        else if (which == 2) Vs[r] = *(const float4*)(pred + off);
        else                 Ss[r] = *(const float4*)(state + off);
    }
    __syncthreads();

    const int tr = t >> 4;          // row group: rows 4tr..4tr+3
    const int tc = t & 15;          // col group: cols 4tc..4tc+3
    const int wv = t >> 6;
    const int l  = t & 63;

    // ---- scores into registers, with sum-of-squares and max ----
    float p00, p01, p02, p03, p10, p11, p12, p13;
    float p20, p21, p22, p23, p30, p31, p32, p33;
    float ss = 0.f, mx = -1e30f;
    {
        float4 kk0 = Ks[4 * tc + 0];
        float4 kk1 = Ks[4 * tc + 1];
        float4 kk2 = Ks[4 * tc + 2];
        float4 kk3 = Ks[4 * tc + 3];
#define SCORE(q, kkj) ((q.x * kkj.x + q.y * kkj.y + q.z * kkj.z + q.w * kkj.w) * 0.5f)
#define ROW(i)                                                      \
        {                                                           \
            const float4 q = Qs[4 * tr + i];                        \
            p##i##0 = SCORE(q, kk0); p##i##1 = SCORE(q, kk1);       \
            p##i##2 = SCORE(q, kk2); p##i##3 = SCORE(q, kk3);       \
            ss += p##i##0 * p##i##0 + p##i##1 * p##i##1 +           \
                  p##i##2 * p##i##2 + p##i##3 * p##i##3;            \
            mx = fmaxf(mx, fmaxf(fmaxf(p##i##0, p##i##1),           \
                                 fmaxf(p##i##2, p##i##3)));         \
        }
        ROW(0) ROW(1) ROW(2) ROW(3)
#undef ROW
#undef SCORE
    }
#pragma unroll
    for (int o = 32; o >= 1; o >>= 1) {
        ss += __shfl_xor(ss, o, 64);
        mx = fmaxf(mx, __shfl_xor(mx, o, 64));
    }
    if (l == 0) { redS[wv] = ss; redM[wv] = mx; }
    __syncthreads();
    ss = redS[0] + redS[1] + redS[2] + redS[3];
    mx = fmaxf(fmaxf(redM[0], redM[1]), fmaxf(redM[2], redM[3]));
    const float scale = rsqrtf(ss * (1.0f / 4096.0f) + 1e-6f);  // SHARPNESS=1

#define EXPIJ(v) v = expf(scale * (v - mx))
    EXPIJ(p00); EXPIJ(p01); EXPIJ(p02); EXPIJ(p03);
    EXPIJ(p10); EXPIJ(p11); EXPIJ(p12); EXPIJ(p13);
    EXPIJ(p20); EXPIJ(p21); EXPIJ(p22); EXPIJ(p23);
    EXPIJ(p30); EXPIJ(p31); EXPIJ(p32); EXPIJ(p33);
#undef EXPIJ

    // ---- sinkhorn: 10 x (row-normalize, col-normalize) ----
    int buf = 0;
    for (int it = 0; it < 10; ++it) {
        // row phase: sums over the 16 tc-groups (wave-local lanes)
        float r0 = p00 + p01 + p02 + p03;
        float r1 = p10 + p11 + p12 + p13;
        float r2 = p20 + p21 + p22 + p23;
        float r3 = p30 + p31 + p32 + p33;
#pragma unroll
        for (int o = 1; o <= 8; o <<= 1) {
            r0 += __shfl_xor(r0, o, 64);
            r1 += __shfl_xor(r1, o, 64);
            r2 += __shfl_xor(r2, o, 64);
            r3 += __shfl_xor(r3, o, 64);
        }
        {
            const float i0 = 1.0f / (r0 + EPS_SINK);
            const float i1 = 1.0f / (r1 + EPS_SINK);
            const float i2 = 1.0f / (r2 + EPS_SINK);
            const float i3 = 1.0f / (r3 + EPS_SINK);
            p00 *= i0; p01 *= i0; p02 *= i0; p03 *= i0;
            p10 *= i1; p11 *= i1; p12 *= i1; p13 *= i1;
            p20 *= i2; p21 *= i2; p22 *= i2; p23 *= i2;
            p30 *= i3; p31 *= i3; p32 *= i3; p33 *= i3;
        }

        // col phase: sums over the 16 tr-groups (4 wave-local + cross-wave LDS)
        float c0 = p00 + p10 + p20 + p30;
        float c1 = p01 + p11 + p21 + p31;
        float c2 = p02 + p12 + p22 + p32;
        float c3 = p03 + p13 + p23 + p33;
#pragma unroll
        for (int o = 16; o <= 32; o <<= 1) {
            c0 += __shfl_xor(c0, o, 64);
            c1 += __shfl_xor(c1, o, 64);
            c2 += __shfl_xor(c2, o, 64);
            c3 += __shfl_xor(c3, o, 64);
        }
        if (l < 16) {   // l == tc for these lanes
            cp[buf][wv][4 * l + 0] = c0;
            cp[buf][wv][4 * l + 1] = c1;
            cp[buf][wv][4 * l + 2] = c2;
            cp[buf][wv][4 * l + 3] = c3;
        }
        __syncthreads();
        {
            const float4 a0 = *(const float4*)&cp[buf][0][4 * tc];
            const float4 a1 = *(const float4*)&cp[buf][1][4 * tc];
            const float4 a2 = *(const float4*)&cp[buf][2][4 * tc];
            const float4 a3 = *(const float4*)&cp[buf][3][4 * tc];
            const float i0 = 1.0f / (a0.x + a1.x + a2.x + a3.x + EPS_SINK);
            const float i1 = 1.0f / (a0.y + a1.y + a2.y + a3.y + EPS_SINK);
            const float i2 = 1.0f / (a0.z + a1.z + a2.z + a3.z + EPS_SINK);
            const float i3 = 1.0f / (a0.w + a1.w + a2.w + a3.w + EPS_SINK);
            p00 *= i0; p10 *= i0; p20 *= i0; p30 *= i0;
            p01 *= i1; p11 *= i1; p21 *= i1; p31 *= i1;
            p02 *= i2; p12 *= i2; p22 *= i2; p32 *= i2;
            p03 *= i3; p13 *= i3; p23 *= i3; p33 *= i3;
        }
        buf ^= 1;
    }

    // ---- threshold and stage A into LDS ----
#define STORE_A(i, j, v) P[(4 * tr + i) * 65 + 4 * tc + j] = ((v) > THR) ? (v) : 0.f
    STORE_A(0, 0, p00); STORE_A(0, 1, p01); STORE_A(0, 2, p02); STORE_A(0, 3, p03);
    STORE_A(1, 0, p10); STORE_A(1, 1, p11); STORE_A(1, 2, p12); STORE_A(1, 3, p13);
    STORE_A(2, 0, p20); STORE_A(2, 1, p21); STORE_A(2, 2, p22); STORE_A(2, 3, p23);
    STORE_A(3, 0, p30); STORE_A(3, 1, p31); STORE_A(3, 2, p32); STORE_A(3, 3, p33);
#undef STORE_A
    __syncthreads();

    // ---- routed_V + fused loss partials for elements (b, n, h*4+d) ----
    float l1, l2, l3;
    {
        const int d = t & 3;
        const int n = t >> 2;
        const float* Vf = (const float*)Vs;
        const float* Kf = (const float*)Ks;
        const float* Qf = (const float*)Qs;
        const float* Sf = (const float*)Ss;
        float acc = 0.f;
#pragma unroll 8
        for (int mm = 0; mm < 64; ++mm) {
            acc = fmaf(P[n * 65 + mm], Vf[mm * 4 + d], acc);
        }
        // target value for this element
        float tv;
        if (n == 0) {
            tv = env[b * 100 + h * 4 + d];
        } else if (n == 1) {
            const int idx = 64 + h * 4 + d;
            tv = (idx < 100) ? env[b * 100 + idx] : 0.f;
        } else {
            tv = acc;
        }
        const float pv = Vf[n * 4 + d];
        const float kk = Kf[n * 4 + d];
        const float qv = Qf[n * 4 + d];
        const float sv = Sf[n * 4 + d];
        const float d1 = pv - tv;
        const float d2 = kk - sv;
        const float d3 = qv - tv;
        l1 = d1 * d1; l2 = d2 * d2; l3 = d3 * d3;
    }
#pragma unroll
    for (int o = 32; o >= 1; o >>= 1) {
        l1 += __shfl_xor(l1, o, 64);
        l2 += __shfl_xor(l2, o, 64);
        l3 += __shfl_xor(l3, o, 64);
    }
    if (l == 0) { red[wv] = l1; red[4 + wv] = l2; red[8 + wv] = l3; }
    __syncthreads();
    if (t == 0) {
        part[blk]        = red[0] + red[1] + red[2] + red[3];
        part[4096 + blk] = red[4] + red[5] + red[6] + red[7];
        part[8192 + blk] = red[8] + red[9] + red[10] + red[11];
    }
}

// ---------------------------------------------------------------------------
// K3: final reduce -> scalar loss
// ---------------------------------------------------------------------------
__global__ __launch_bounds__(256) void loss_final_kernel(
    const float* __restrict__ part, float* __restrict__ out)
{
    float a = 0.f;
    for (int i = threadIdx.x; i < 12288; i += 256) a += part[i];
#pragma unroll
    for (int o = 32; o >= 1; o >>= 1) a += __shfl_xor(a, o, 64);
    __shared__ float red[4];
    const int wv = threadIdx.x >> 6, ln = threadIdx.x & 63;
    if (ln == 0) red[wv] = a;
    __syncthreads();
    if (threadIdx.x == 0) {
        out[0] = (red[0] + red[1] + red[2] + red[3]) * (1.0f / (float)TOT);
    }
}

extern "C" void kernel_launch(void* const* d_in, const int* in_sizes, int n_in,
                              void* d_out, int out_size, void* d_ws, size_t ws_size,
                              hipStream_t stream)
{
    const float* env   = (const float*)d_in[0];
    const float* state = (const float*)d_in[1];
    const float* w1    = (const float*)d_in[2];
    const float* w2    = (const float*)d_in[3];
    const float* w3    = (const float*)d_in[4];
    float* out = (float*)d_out;

    float* wsf  = (float*)d_ws;
    float* pred = wsf;
    float* keys = wsf + 1 * TOT;
    float* quer = wsf + 2 * TOT;
    float* part = wsf + 3 * TOT;   // 3*4096 floats

    hipLaunchKernelGGL(gemv_buntanh_kernel, dim3(1536), dim3(256), 0, stream,
                       state, w1, w2, w3, pred, keys, quer);
    hipLaunchKernelGGL(attn_sinkhorn_loss_kernel, dim3(4096), dim3(256), 0, stream,
                       pred, keys, quer, state, env, part);
    hipLaunchKernelGGL(loss_final_kernel, dim3(1), dim3(256), 0, stream,
                       part, out);
}